// Round 1
// 59.858 us; speedup vs baseline: 1.0074x; 1.0074x over previous
//
#include <hip/hip_runtime.h>
#include <math.h>

#define WIN 1024
#define NH 64
#define YSZ 1056   // 1024 data + 3x4 inter-chunk pad + tail pad for prefetch overrun

// Goertzel, one block (4 waves) per frame.
// NEW MAPPING (Nyquist-skip): wave w owns harmonics k = 16w+1 .. 16w+16.
//   lane = c*16 + h : c = 256-sample chunk (0..3), h = harmonic-in-wave (0..15).
// Each lane runs two independent 128-step Goertzel chains over its chunk
// (same verified partial-combine math as before:
//   chain over samples [s, s+128) contributes e^{-j*2pi*fc*(s+127)} * (ur + j*ui)).
// Cross-chunk combine via __shfl_xor(16) + __shfl_xor(32)  (no LDS partials).
// A wave whose SMALLEST k is above Nyquist (f0*(16w+1) > 8000) skips the whole
// main loop -- on f0 ~ U[50,500) that kills ~35% of the Goertzel work that the
// old all-k-per-wave mapping computed and then masked to zero.
// LDS layout: +4-float pad after each 256-float chunk so the 4 broadcast-group
// addresses of each ds_read_b128 hit disjoint bank quads (conflict-free).
__global__ __launch_bounds__(256) void morlet_goertzel(
    const float* __restrict__ x,    // [F, 1024]
    const float* __restrict__ f0,   // [F]
    float* __restrict__ hd,         // [F, 64]
    float* __restrict__ amp)        // [F]
{
    const int frame = blockIdx.x;
    const int tid   = threadIdx.x;
    const int lane  = tid & 63;
    const int wave  = tid >> 6;

    __shared__ float y[YSZ];
    __shared__ float mag[NH];

    const float f0v = f0[frame];

    // ---- stage windowed frame into LDS (float4 per thread, padded layout) ----
    {
        const float4 v =
            reinterpret_cast<const float4*>(x + (size_t)frame * WIN)[tid];
        const float inv_tp = 1.0f / 16000.0f;
        const float norm   = 0.0044603129f;    // 1/sqrt(pi*16000)
        const int n0 = 4 * tid;
        const int p0 = n0 + ((n0 >> 8) << 2);  // +4 floats per 256-sample chunk
        const float d0 = (float)(n0 - 512);
        const float d1 = d0 + 1.0f;
        const float d2 = d0 + 2.0f;
        const float d3 = d0 + 3.0f;
        y[p0 + 0] = v.x * (norm * __expf(-d0 * d0 * inv_tp));
        y[p0 + 1] = v.y * (norm * __expf(-d1 * d1 * inv_tp));
        y[p0 + 2] = v.z * (norm * __expf(-d2 * d2 * inv_tp));
        y[p0 + 3] = v.w * (norm * __expf(-d3 * d3 * inv_tp));
        // zero pad gaps + tail (read only by dead last-iteration prefetch)
        if (tid < 4) { y[256 + tid] = 0.0f; y[516 + tid] = 0.0f; y[776 + tid] = 0.0f; }
        if (tid < YSZ - 1036) y[1036 + tid] = 0.0f;
    }
    __syncthreads();

    // wave-uniform Nyquist skip: smallest k in this wave is 16*wave+1
    const bool active = (f0v * (float)(16 * wave + 1) <= 8000.0f);

    if (active) {
        const int c = lane >> 4;               // sample chunk (256 samples)
        const int h = lane & 15;               // harmonic within wave band
        const int k = 16 * wave + h + 1;
        const float fc = f0v * (float)k * (1.0f / 16000.0f);   // rev/sample
        const float tw = fc - floorf(fc);
        const float c1  = __builtin_amdgcn_cosf(tw);  // cos(2*pi*fc)
        const float sn1 = __builtin_amdgcn_sinf(tw);  // sin(2*pi*fc)
        const float coef = 2.0f * c1;

        float a1 = 0.0f, a2 = 0.0f, b1 = 0.0f, b2 = 0.0f;

#define GSTEP(ch1, ch2, yv) { const float t_ = fmaf(coef, ch1, (yv) - ch2); ch2 = ch1; ch1 = t_; }

        const int base = 260 * c;              // padded chunk start
        // chain A: samples [256c, 256c+128) ; chain B: [256c+128, 256c+256)
        float4 A0 = *(const float4*)&y[base];
        float4 A1 = *(const float4*)&y[base + 4];
        float4 B0 = *(const float4*)&y[base + 128];
        float4 B1 = *(const float4*)&y[base + 132];

        #pragma unroll 4
        for (int i = 0; i < 128; i += 8) {
            const float4 nA0 = *(const float4*)&y[base + i + 8];
            const float4 nA1 = *(const float4*)&y[base + i + 12];
            const float4 nB0 = *(const float4*)&y[base + 128 + i + 8];  // last iter hits pad
            const float4 nB1 = *(const float4*)&y[base + 128 + i + 12];
            GSTEP(a1, a2, A0.x) GSTEP(a1, a2, A0.y) GSTEP(a1, a2, A0.z) GSTEP(a1, a2, A0.w)
            GSTEP(a1, a2, A1.x) GSTEP(a1, a2, A1.y) GSTEP(a1, a2, A1.z) GSTEP(a1, a2, A1.w)
            GSTEP(b1, b2, B0.x) GSTEP(b1, b2, B0.y) GSTEP(b1, b2, B0.z) GSTEP(b1, b2, B0.w)
            GSTEP(b1, b2, B1.x) GSTEP(b1, b2, B1.y) GSTEP(b1, b2, B1.z) GSTEP(b1, b2, B1.w)
            A0 = nA0; A1 = nA1; B0 = nB0; B1 = nB1;
        }
#undef GSTEP

        // chain partial: e^{-jw(s+127)} * ((s1 - c1*s2) + j*sn1*s2), s = chain start
        float tA = fc * (float)(256 * c + 127); tA -= floorf(tA);
        float tB = fc * (float)(256 * c + 255); tB -= floorf(tB);
        const float cA = __builtin_amdgcn_cosf(tA), sA = __builtin_amdgcn_sinf(tA);
        const float cB = __builtin_amdgcn_cosf(tB), sB = __builtin_amdgcn_sinf(tB);

        const float urA = fmaf(-c1, a2, a1);
        const float uiA = sn1 * a2;
        const float urB = fmaf(-c1, b2, b1);
        const float uiB = sn1 * b2;

        float reW = fmaf(cA, urA,  sA * uiA) + fmaf(cB, urB,  sB * uiB);
        float imW = fmaf(cA, uiA, -sA * urA) + fmaf(cB, uiB, -sB * urB);

        // combine 4 chunk-partials per harmonic (lanes h, h+16, h+32, h+48)
        reW += __shfl_xor(reW, 16, 64);  imW += __shfl_xor(imW, 16, 64);
        reW += __shfl_xor(reW, 32, 64);  imW += __shfl_xor(imW, 32, 64);

        if (lane < 16) {
            const float v = (fc <= 0.5f) ? sqrtf(fmaf(reW, reW, imW * imW)) : 0.0f;
            mag[16 * wave + lane] = v;
        }
    } else if (lane < 16) {
        mag[16 * wave + lane] = 0.0f;    // whole band above Nyquist
    }
    __syncthreads();

    // ---- wave 0: normalize across the 64 harmonics, write out ----
    if (tid < NH) {
        const float v = mag[tid];
        float s = v;
        #pragma unroll
        for (int off = 32; off > 0; off >>= 1) s += __shfl_xor(s, off, 64);
        hd[(size_t)frame * NH + tid] = v / s;
        if (tid == 0) amp[frame] = fminf(fmaxf(s * 2.0f, 0.0f), 1.0f);
    }
}

extern "C" void kernel_launch(void* const* d_in, const int* in_sizes, int n_in,
                              void* d_out, int out_size, void* d_ws, size_t ws_size,
                              hipStream_t stream) {
    const float* x   = (const float*)d_in[0];    // audio_frames [B,T,C,1024] f32
    const float* f0  = (const float*)d_in[1];    // f0 [B,T,C] f32
    const int F = in_sizes[1];                   // B*T*C frames (800)
    float* hd  = (float*)d_out;                  // [F,64]
    float* amp = (float*)d_out + (size_t)F * NH; // [F]
    morlet_goertzel<<<F, 256, 0, stream>>>(x, f0, hd, amp);
}